// Round 1
// baseline (906.597 us; speedup 1.0000x reference)
//
#include <hip/hip_runtime.h>
#include <hip/hip_bf16.h>

// AttentionAggregator2: N=16384 nodes, K=32 neighbors, D=256, E=64, H=64, O=256.
// logit[n,k] = dot(tanh(NC[n,k] @ att2_w1^T), v[n]);  v[n] = M * tanh(att_w1 @ x[n]),
// M = att2_w2^T @ att_w2 (precomputed).  agg = softmax(logit) @ NC.
// out = relu([x@fcx^T, agg@fcn^T]).

typedef float  f32x4  __attribute__((ext_vector_type(4)));
typedef float  f32x16 __attribute__((ext_vector_type(16)));
typedef short  s16x8  __attribute__((ext_vector_type(8)));

__device__ __forceinline__ unsigned pk_bf16(float a, float b) {
  unsigned r;
  asm("v_cvt_pk_bf16_f32 %0, %1, %2" : "=v"(r) : "v"(a), "v"(b));
  return r;
}
__device__ __forceinline__ unsigned short bf16_1(float a) {
  return (unsigned short)(pk_bf16(a, a) & 0xffffu);
}
__device__ __forceinline__ s16x8 frag8(float4 a, float4 b) {
  union { s16x8 v; unsigned u[4]; } r;
  r.u[0] = pk_bf16(a.x, a.y);
  r.u[1] = pk_bf16(a.z, a.w);
  r.u[2] = pk_bf16(b.x, b.y);
  r.u[3] = pk_bf16(b.z, b.w);
  return r.v;
}
__device__ __forceinline__ float tanh_fast(float x) {
  float e = __expf(2.0f * x);                       // handles +-inf correctly
  return 1.0f - 2.0f * __builtin_amdgcn_rcpf(e + 1.0f);
}
// XOR swizzle for the [32][320] bf16 node tile (row stride 640B = 5*128B).
// Toggles byte bits 4-6 only -> stays within the row's 128B window, keeps 16B granules.
__device__ __forceinline__ int swz(int row, int byte) {
  return row * 640 + (byte ^ (((row & 7) << 4) ^ ((row >> 3) << 5)));
}

// ---------------- kernel 1: weight prep (bf16 conversions + M = att2_w2^T @ att_w2) ----
__global__ void k_prep(const float* __restrict__ att_w1, const float* __restrict__ att_w2,
                       const float* __restrict__ att2_w1, const float* __restrict__ att2_w2,
                       const float* __restrict__ fcx, const float* __restrict__ fcn,
                       unsigned short* __restrict__ W1B, unsigned short* __restrict__ A1B,
                       unsigned short* __restrict__ Mbf, unsigned short* __restrict__ FXB,
                       unsigned short* __restrict__ FNB) {
  if (blockIdx.x == 64) {
    for (int t = threadIdx.x; t < 64 * 64; t += 256) {
      int j2 = t >> 6, j = t & 63;
      float s = 0.f;
      for (int h = 0; h < 64; ++h) s += att2_w2[h * 64 + j2] * att_w2[h * 64 + j];
      Mbf[t] = bf16_1(s);                            // row-major [j2][j]
    }
    return;
  }
  const int total = 20480 + 16384 + 65536 + 81920;
  for (int i = blockIdx.x * 256 + threadIdx.x; i < total; i += 64 * 256) {
    if (i < 20480)       W1B[i]          = bf16_1(att2_w1[i]);
    else if (i < 36864)  A1B[i - 20480]  = bf16_1(att_w1[i - 20480]);
    else if (i < 102400) FXB[i - 36864]  = bf16_1(fcx[i - 36864]);
    else                 FNB[i - 102400] = bf16_1(fcn[i - 102400]);
  }
}

// ---------------- kernel 2: V[n] = M * tanh(att_w1 @ x[n]) -----------------------------
__global__ __launch_bounds__(256) void k_vcalc(const float* __restrict__ x,
    const unsigned short* __restrict__ A1B, const unsigned short* __restrict__ Mbf,
    float* __restrict__ V) {
  __shared__ __align__(16) unsigned short T[4][32 * 64];   // per-wave tanh tile, swizzled
  const int w = threadIdx.x >> 6, l = threadIdx.x & 63;
  const int l31 = l & 31, hf = l >> 5;
  const long n0 = (long)(blockIdx.x * 4 + w) * 32;
  f32x16 a0, a1;
  #pragma unroll
  for (int i = 0; i < 16; ++i) { a0[i] = 0.f; a1[i] = 0.f; }
  #pragma unroll 4
  for (int s = 0; s < 16; ++s) {                    // K = 256, k-step 16
    const float4* xp = reinterpret_cast<const float4*>(x + (n0 + l31) * 256 + 16 * s + 8 * hf);
    s16x8 af = frag8(xp[0], xp[1]);
    s16x8 b0 = *reinterpret_cast<const s16x8*>(A1B + l31 * 256 + 16 * s + 8 * hf);
    s16x8 b1 = *reinterpret_cast<const s16x8*>(A1B + (l31 + 32) * 256 + 16 * s + 8 * hf);
    a0 = __builtin_amdgcn_mfma_f32_32x32x16_bf16(af, b0, a0, 0, 0, 0);
    a1 = __builtin_amdgcn_mfma_f32_32x32x16_bf16(af, b1, a1, 0, 0, 0);
  }
  #pragma unroll
  for (int r = 0; r < 16; ++r) {
    int row = (r & 3) + 8 * (r >> 2) + 4 * hf;       // C/D layout 32x32 (m74/m101)
    T[w][(row << 6) + (l31 ^ ((row & 7) << 3))]        = bf16_1(tanh_fast(a0[r]));
    T[w][(row << 6) + ((32 + l31) ^ ((row & 7) << 3))] = bf16_1(tanh_fast(a1[r]));
  }
  f32x16 c0, c1;
  #pragma unroll
  for (int i = 0; i < 16; ++i) { c0[i] = 0.f; c1[i] = 0.f; }
  #pragma unroll
  for (int s = 0; s < 4; ++s) {                      // K = 64
    s16x8 af = *reinterpret_cast<const s16x8*>(
        &T[w][(l31 << 6) + ((16 * s + 8 * hf) ^ ((l31 & 7) << 3))]);
    s16x8 b0 = *reinterpret_cast<const s16x8*>(Mbf + l31 * 64 + 16 * s + 8 * hf);
    s16x8 b1 = *reinterpret_cast<const s16x8*>(Mbf + (l31 + 32) * 64 + 16 * s + 8 * hf);
    c0 = __builtin_amdgcn_mfma_f32_32x32x16_bf16(af, b0, c0, 0, 0, 0);
    c1 = __builtin_amdgcn_mfma_f32_32x32x16_bf16(af, b1, c1, 0, 0, 0);
  }
  #pragma unroll
  for (int r = 0; r < 16; ++r) {
    int row = (r & 3) + 8 * (r >> 2) + 4 * hf;
    V[(n0 + row) * 64 + l31]      = c0[r];
    V[(n0 + row) * 64 + 32 + l31] = c1[r];
  }
}

// ---------------- kernel 3: fused attention + aggregation (one 64-thr block per node) --
__global__ __launch_bounds__(64) void k_fused(const float* __restrict__ neibs,
    const float* __restrict__ edge, const float* __restrict__ mask,
    const float* __restrict__ V, const unsigned short* __restrict__ W1B,
    float* __restrict__ AGG) {
  __shared__ __align__(16) char lds[32 * 640 + 128];   // NC bf16 tile + ws[32] f32
  const int n = blockIdx.x;
  const int l = threadIdx.x;
  const int g = l >> 4, c = l & 15;
  // ---- stage NC = [neibs | edge] rows as bf16, swizzled (single HBM read) ----
  {
    const float4* nb = reinterpret_cast<const float4*>(neibs + (long)n * (32 * 256));
    #pragma unroll 8
    for (int i = 0; i < 32; ++i) {                   // one full row per iter, coalesced 1KB
      float4 v4 = nb[i * 64 + l];
      uint2 t; t.x = pk_bf16(v4.x, v4.y); t.y = pk_bf16(v4.z, v4.w);
      *reinterpret_cast<uint2*>(lds + swz(i, l * 8)) = t;
    }
    const float4* eb = reinterpret_cast<const float4*>(edge + (long)n * (32 * 64));
    #pragma unroll
    for (int j = 0; j < 8; ++j) {                    // 4 edge rows per iter
      float4 v4 = eb[j * 64 + l];
      uint2 t; t.x = pk_bf16(v4.x, v4.y); t.y = pk_bf16(v4.z, v4.w);
      *reinterpret_cast<uint2*>(lds + swz(4 * j + g, 512 + 8 * c)) = t;
    }
  }
  // ---- S^T = att2_w1 @ NC^T  (rows = hidden j2, cols = neighbor k) ----
  f32x4 acc[4][2];
  #pragma unroll
  for (int rt = 0; rt < 4; ++rt) {
    #pragma unroll
    for (int ct = 0; ct < 2; ++ct) acc[rt][ct] = (f32x4){0.f, 0.f, 0.f, 0.f};
  }
  #pragma unroll 2
  for (int s = 0; s < 10; ++s) {                     // K = 320, k-step 32
    s16x8 bf0 = *reinterpret_cast<const s16x8*>(lds + swz(c,      64 * s + 16 * g));
    s16x8 bf1 = *reinterpret_cast<const s16x8*>(lds + swz(16 + c, 64 * s + 16 * g));
    #pragma unroll
    for (int rt = 0; rt < 4; ++rt) {
      s16x8 af = *reinterpret_cast<const s16x8*>(W1B + (16 * rt + c) * 320 + 32 * s + 8 * g);
      acc[rt][0] = __builtin_amdgcn_mfma_f32_16x16x32_bf16(af, bf0, acc[rt][0], 0, 0, 0);
      acc[rt][1] = __builtin_amdgcn_mfma_f32_16x16x32_bf16(af, bf1, acc[rt][1], 0, 0, 0);
    }
  }
  // ---- logits: p[k] = sum_j2 tanh(S^T[j2][k]) * v[j2]  (contraction over C-rows) ----
  float p0 = 0.f, p1 = 0.f;
  #pragma unroll
  for (int rt = 0; rt < 4; ++rt) {
    float4 vv = *reinterpret_cast<const float4*>(V + n * 64 + 16 * rt + 4 * g);
    const float* vp = reinterpret_cast<const float*>(&vv);
    #pragma unroll
    for (int rr = 0; rr < 4; ++rr) {
      p0 += tanh_fast(acc[rt][0][rr]) * vp[rr];
      p1 += tanh_fast(acc[rt][1][rr]) * vp[rr];
    }
  }
  p0 += __shfl_xor(p0, 16); p0 += __shfl_xor(p0, 32);  // reduce over lane-groups
  p1 += __shfl_xor(p1, 16); p1 += __shfl_xor(p1, 32);
  float lg0 = p0 * 0.125f - 9999999.f * mask[n * 32 + c];        // /sqrt(64) + mask
  float lg1 = p1 * 0.125f - 9999999.f * mask[n * 32 + 16 + c];
  float mx = fmaxf(lg0, lg1);
  mx = fmaxf(mx, __shfl_xor(mx, 1)); mx = fmaxf(mx, __shfl_xor(mx, 2));
  mx = fmaxf(mx, __shfl_xor(mx, 4)); mx = fmaxf(mx, __shfl_xor(mx, 8));
  float e0 = __expf(lg0 - mx), e1 = __expf(lg1 - mx);
  float sm = e0 + e1;
  sm += __shfl_xor(sm, 1); sm += __shfl_xor(sm, 2);
  sm += __shfl_xor(sm, 4); sm += __shfl_xor(sm, 8);
  float inv = __builtin_amdgcn_rcpf(sm);
  float* wsl = reinterpret_cast<float*>(lds + 32 * 640);
  if (l < 16) { wsl[l] = e0 * inv; wsl[l + 16] = e1 * inv; }
  // ---- agg[d] = sum_k ws[k] * NC[k][d]  (fp32 accumulate; lane l owns cols 8l..8l+7) --
  if (l < 40) {
    float a8[8];
    #pragma unroll
    for (int q = 0; q < 8; ++q) a8[q] = 0.f;
    #pragma unroll 8
    for (int k = 0; k < 32; ++k) {
      float wk = wsl[k];                             // LDS broadcast
      union { s16x8 v; unsigned u[4]; } nc;
      nc.v = *reinterpret_cast<const s16x8*>(lds + swz(k, 16 * l));
      #pragma unroll
      for (int q = 0; q < 4; ++q) {
        a8[2 * q]     += wk * __uint_as_float(nc.u[q] << 16);
        a8[2 * q + 1] += wk * __uint_as_float(nc.u[q] & 0xffff0000u);
      }
    }
    float4 o0, o1;
    o0.x = a8[0]; o0.y = a8[1]; o0.z = a8[2]; o0.w = a8[3];
    o1.x = a8[4]; o1.y = a8[5]; o1.z = a8[6]; o1.w = a8[7];
    float4* op = reinterpret_cast<float4*>(AGG + (long)n * 320 + 8 * l);
    op[0] = o0; op[1] = o1;
  }
}

// ---------------- kernel 4: out = relu([x@fcx^T , agg@fcn^T]) --------------------------
__global__ __launch_bounds__(256) void k_out(const float* __restrict__ x,
    const float* __restrict__ AGG, const unsigned short* __restrict__ FXB,
    const unsigned short* __restrict__ FNB, float* __restrict__ out) {
  const int w = threadIdx.x >> 6, l = threadIdx.x & 63;
  const int l31 = l & 31, hf = l >> 5;
  const long n0 = (long)blockIdx.x * 32;
  f32x16 c0, c1;
  #pragma unroll
  for (int i = 0; i < 16; ++i) { c0[i] = 0.f; c1[i] = 0.f; }
  if (blockIdx.y == 0) {
    #pragma unroll 4
    for (int s = 0; s < 16; ++s) {                   // K = 256
      const float4* xp = reinterpret_cast<const float4*>(x + (n0 + l31) * 256 + 16 * s + 8 * hf);
      s16x8 af = frag8(xp[0], xp[1]);
      s16x8 b0 = *reinterpret_cast<const s16x8*>(FXB + (64 * w + l31) * 256 + 16 * s + 8 * hf);
      s16x8 b1 = *reinterpret_cast<const s16x8*>(FXB + (64 * w + 32 + l31) * 256 + 16 * s + 8 * hf);
      c0 = __builtin_amdgcn_mfma_f32_32x32x16_bf16(af, b0, c0, 0, 0, 0);
      c1 = __builtin_amdgcn_mfma_f32_32x32x16_bf16(af, b1, c1, 0, 0, 0);
    }
    #pragma unroll
    for (int r = 0; r < 16; ++r) {
      int row = (r & 3) + 8 * (r >> 2) + 4 * hf;
      out[(n0 + row) * 512 + 64 * w + l31]      = fmaxf(c0[r], 0.f);
      out[(n0 + row) * 512 + 64 * w + 32 + l31] = fmaxf(c1[r], 0.f);
    }
  } else {
    #pragma unroll 4
    for (int s = 0; s < 20; ++s) {                   // K = 320
      const float4* ap = reinterpret_cast<const float4*>(AGG + (n0 + l31) * 320 + 16 * s + 8 * hf);
      s16x8 af = frag8(ap[0], ap[1]);
      s16x8 b0 = *reinterpret_cast<const s16x8*>(FNB + (64 * w + l31) * 320 + 16 * s + 8 * hf);
      s16x8 b1 = *reinterpret_cast<const s16x8*>(FNB + (64 * w + 32 + l31) * 320 + 16 * s + 8 * hf);
      c0 = __builtin_amdgcn_mfma_f32_32x32x16_bf16(af, b0, c0, 0, 0, 0);
      c1 = __builtin_amdgcn_mfma_f32_32x32x16_bf16(af, b1, c1, 0, 0, 0);
    }
    #pragma unroll
    for (int r = 0; r < 16; ++r) {
      int row = (r & 3) + 8 * (r >> 2) + 4 * hf;
      out[(n0 + row) * 512 + 256 + 64 * w + l31]      = fmaxf(c0[r], 0.f);
      out[(n0 + row) * 512 + 256 + 64 * w + 32 + l31] = fmaxf(c1[r], 0.f);
    }
  }
}

extern "C" void kernel_launch(void* const* d_in, const int* in_sizes, int n_in,
                              void* d_out, int out_size, void* d_ws, size_t ws_size,
                              hipStream_t stream) {
  const float* x    = (const float*)d_in[0];
  const float* nb   = (const float*)d_in[1];
  const float* ee   = (const float*)d_in[2];
  const float* mk   = (const float*)d_in[3];
  const float* aw1  = (const float*)d_in[4];
  const float* aw2  = (const float*)d_in[5];
  const float* a2w1 = (const float*)d_in[6];
  const float* a2w2 = (const float*)d_in[7];
  const float* fcx  = (const float*)d_in[8];
  const float* fcn  = (const float*)d_in[9];
  float* out = (float*)d_out;
  const int N = in_sizes[0] / 256;

  char* ws = (char*)d_ws;
  float* AGG = (float*)ws;                                   // N*320 f32
  float* V   = (float*)(ws + (size_t)N * 320 * 4);           // N*64  f32
  unsigned short* W1B = (unsigned short*)(ws + (size_t)N * (320 + 64) * 4);
  unsigned short* A1B = W1B + 64 * 320;
  unsigned short* Mbf = A1B + 64 * 256;
  unsigned short* FXB = Mbf + 64 * 64;
  unsigned short* FNB = FXB + 256 * 256;

  k_prep<<<65, 256, 0, stream>>>(aw1, aw2, a2w1, a2w2, fcx, fcn, W1B, A1B, Mbf, FXB, FNB);
  k_vcalc<<<N / 128, 256, 0, stream>>>(x, A1B, Mbf, V);
  k_fused<<<N, 64, 0, stream>>>(nb, ee, mk, V, W1B, AGG);
  k_out<<<dim3(N / 32, 2), 256, 0, stream>>>(x, AGG, FXB, FNB, out);
}